// Round 11
// baseline (675.701 us; speedup 1.0000x reference)
//
#include <hip/hip_runtime.h>
#include <hip/hip_bf16.h>
#include <math.h>

#define HID 128
#define ET  64          // edges per block (edge MLP), 16/wave
#define K1  288         // padded K for layer 1 (268 -> 9*32)
#define Z1S 136         // S slab stride in bf16
#define Z2S 69          // z2 slab stride in fp32
#define SLAB 4480       // per-wave LDS slab bytes (>= 16*Z1S*2 and 16*Z2S*4)
#define SMS 136         // sage_pq h-transpose LDS stride in bf16

typedef __attribute__((ext_vector_type(8))) short short8;   // 8 bf16 = 4 VGPRs
typedef __attribute__((ext_vector_type(4))) float floatx4;  // MFMA accumulator

// HW packed convert: v_cvt_pk_bf16_f32 (RNE), lo -> low 16 bits
static __device__ __forceinline__ unsigned pack2bf(float lo, float hi) {
    __hip_bfloat162 v = __float22bfloat162_rn(float2{lo, hi});
    union { __hip_bfloat162 b; unsigned u; } cv; cv.b = v; return cv.u;
}
static __device__ __forceinline__ unsigned short f2bf16(float v) {
    return (unsigned short)pack2bf(v, v);
}
static __device__ __forceinline__ float bf2f_lo(unsigned u) { return __uint_as_float(u << 16); }
static __device__ __forceinline__ float bf2f_hi(unsigned u) { return __uint_as_float(u & 0xffff0000u); }

// ---------- CSR build ----------
__global__ void hist_kernel(const int* __restrict__ dst, unsigned* __restrict__ deg, int E) {
    int e = blockIdx.x * 256 + threadIdx.x;
    if (e < E) atomicAdd(&deg[dst[e]], 1u);
}

__global__ __launch_bounds__(256) void scan_partial(const unsigned* __restrict__ deg,
        unsigned* __restrict__ off, unsigned* __restrict__ bsum, int N) {
    int t = threadIdx.x;
    int base = blockIdx.x * 2048 + t * 8;
    unsigned v[8]; unsigned run = 0;
#pragma unroll
    for (int i = 0; i < 8; i++) {
        int g = base + i;
        unsigned d = (g < N) ? deg[g] : 0u;
        v[i] = run; run += d;
    }
    __shared__ unsigned s[256];
    s[t] = run; __syncthreads();
    for (int o2 = 1; o2 < 256; o2 <<= 1) {
        unsigned x = (t >= o2) ? s[t - o2] : 0u;
        __syncthreads();
        s[t] += x;
        __syncthreads();
    }
    unsigned texcl = (t > 0) ? s[t - 1] : 0u;
    if (t == 255) bsum[blockIdx.x] = s[255];
#pragma unroll
    for (int i = 0; i < 8; i++) {
        int g = base + i;
        if (g < N) off[g] = texcl + v[i];
    }
}

__global__ void scan_bsum(unsigned* bsum, int B) {   // B <= 64, single wave inclusive
    int t = threadIdx.x;
    unsigned v = (t < B) ? bsum[t] : 0u;
    for (int o = 1; o < 64; o <<= 1) {
        unsigned x = __shfl_up(v, o);
        if (t >= o) v += x;
    }
    if (t < B) bsum[t] = v;
}

__global__ void scan_add(unsigned* __restrict__ off, const unsigned* __restrict__ bsum,
                         unsigned* __restrict__ cur, int N) {
    int g = blockIdx.x * 256 + threadIdx.x;
    if (g >= N) return;
    cur[g] = 0u;
    int blk = g >> 11;
    if (blk > 0) off[g] += bsum[blk - 1];
}

// fills: csrS/csrD/csrE + eattr copied into CSR order as bf16 (24 B/edge)
__global__ void csr_fill(const int* __restrict__ src, const int* __restrict__ dst,
                         const float* __restrict__ eattr,
                         const unsigned* __restrict__ off, unsigned* __restrict__ cur,
                         int* __restrict__ csrS, int* __restrict__ csrD,
                         int* __restrict__ csrE, unsigned short* __restrict__ eattrP, int E) {
    int e = blockIdx.x * 256 + threadIdx.x;
    if (e >= E) return;
    int d = dst[e];
    unsigned p = off[d] + atomicAdd(&cur[d], 1u);
    csrS[p] = src[e];
    csrD[p] = d;
    csrE[p] = e;
    const float* ep = eattr + (size_t)e * 12;
    float4 v0 = *(const float4*)ep;
    float4 v1 = *(const float4*)(ep + 4);
    float4 v2 = *(const float4*)(ep + 8);
    unsigned* op = (unsigned*)(eattrP + (size_t)p * 12);
    op[0] = pack2bf(v0.x, v0.y); op[1] = pack2bf(v0.z, v0.w);
    op[2] = pack2bf(v1.x, v1.y); op[3] = pack2bf(v1.z, v1.w);
    op[4] = pack2bf(v2.x, v2.y); op[5] = pack2bf(v2.z, v2.w);
}

// ---------- node projection (writes bf16 h) ----------
__global__ void node_proj_kernel(const float* __restrict__ x, const float* __restrict__ W,
                                 const float* __restrict__ b, unsigned short* __restrict__ hbf, int N) {
    int i = blockIdx.x * 256 + threadIdx.x;   // over N*64, 2 cols/thread
    if (i >= N * 64) return;
    int n = i >> 6, f2 = (i & 63) * 2;
    float a0 = b[f2], a1 = b[f2 + 1];
#pragma unroll
    for (int k = 0; k < 5; k++) {
        float xv = x[n * 5 + k];
        a0 = fmaf(xv, W[k * HID + f2], a0);
        a1 = fmaf(xv, W[k * HID + f2 + 1], a1);
    }
    *(unsigned*)&hbf[(size_t)n * HID + f2] = pack2bf(a0, a1);
}

// ---------- merged weight prep ----------
__global__ void prep_weights(const float* __restrict__ W1, const float* __restrict__ W2,
                             const float* __restrict__ Wl, const float* __restrict__ Wr,
                             unsigned short* __restrict__ W1T, unsigned short* __restrict__ W2T,
                             unsigned short* __restrict__ WST) {
    int i = blockIdx.x * 256 + threadIdx.x;
    if (i < 128 * K1) {
        int n = i / K1, k = i - n * K1;
        W1T[i] = (k < 268) ? f2bf16(W1[k * HID + n]) : (unsigned short)0;
        return;
    }
    int j = i - 128 * K1;
    if (j < 64 * HID) {
        int n = j >> 7, k = j & 127;
        W2T[j] = f2bf16(W2[k * 64 + n]);
        return;
    }
    int m = j - 64 * HID;
    if (m < 3 * 128 * 256) {
        int l = m >> 15, rem = m & 32767, n = rem >> 8, k = rem & 255;
        float v = (k < 128) ? Wl[l * 16384 + k * 128 + n] : Wr[l * 16384 + (k - 128) * 128 + n];
        WST[m] = f2bf16(v);
    }
}

// ---------- mean aggregation: 4 nodes per wave, 8 rows in flight per group ----------
__global__ __launch_bounds__(256) void agg_csr(const unsigned short* __restrict__ hbf,
        const int* __restrict__ csr, const unsigned* __restrict__ off,
        const unsigned* __restrict__ degu, unsigned short* __restrict__ mean_bf, int N) {
    const int wv = threadIdx.x >> 6, lane = threadIdx.x & 63;
    const int g = lane >> 4, c = lane & 15;
    const int n = (blockIdx.x * 4 + wv) * 4 + g;
    const int nc = n < N ? n : N - 1;
    const unsigned o = off[nc];
    const unsigned d = (n < N) ? degu[nc] : 0u;
    unsigned dmax = d;
    dmax = max(dmax, (unsigned)__shfl_xor((int)dmax, 16));
    dmax = max(dmax, (unsigned)__shfl_xor((int)dmax, 32));

    float acc[8] = {0.f, 0.f, 0.f, 0.f, 0.f, 0.f, 0.f, 0.f};
    for (unsigned i = 0; i < dmax; i += 8) {
        uint4 v[8];
#pragma unroll
        for (int j = 0; j < 8; j++) {
            unsigned p = (i + j < d) ? o + i + j : 0u;
            int s = csr[p];
            v[j] = *(const uint4*)&hbf[(size_t)s * HID + c * 8];
        }
#pragma unroll
        for (int j = 0; j < 8; j++) {
            if (i + j < d) {
                acc[0] += bf2f_lo(v[j].x); acc[1] += bf2f_hi(v[j].x);
                acc[2] += bf2f_lo(v[j].y); acc[3] += bf2f_hi(v[j].y);
                acc[4] += bf2f_lo(v[j].z); acc[5] += bf2f_hi(v[j].z);
                acc[6] += bf2f_lo(v[j].w); acc[7] += bf2f_hi(v[j].w);
            }
        }
    }
    if (n < N) {
        float inv = d ? 1.f / (float)d : 0.f;
        uint4 p;
        p.x = pack2bf(acc[0] * inv, acc[1] * inv);
        p.y = pack2bf(acc[2] * inv, acc[3] * inv);
        p.z = pack2bf(acc[4] * inv, acc[5] * inv);
        p.w = pack2bf(acc[6] * inv, acc[7] * inv);
        *(uint4*)&mean_bf[(size_t)n * HID + c * 8] = p;
    }
}

// ---------- SAGE layer (layers 0,1): h in-place, no LDS ----------
__global__ __launch_bounds__(256) void sage_mfma(
    unsigned short* __restrict__ hbf, const unsigned short* __restrict__ mean_bf,
    const unsigned short* __restrict__ WT,
    const float* __restrict__ bl, const float* __restrict__ g,
    const float* __restrict__ bet, int N) {
    const int t = threadIdx.x, wave = t >> 6, lane = t & 63;
    const int ln15 = lane & 15, quad = lane >> 4;
    const int blkBase = blockIdx.x * 128;

    short8 af[2][8];
#pragma unroll
    for (int tt = 0; tt < 2; tt++) {
        int m = blkBase + tt * 64 + wave * 16 + ln15;
        int mc = m < N ? m : N - 1;
#pragma unroll
        for (int kt = 0; kt < 4; kt++)
            af[tt][kt] = *(const short8*)&mean_bf[(size_t)mc * HID + kt * 32 + quad * 8];
#pragma unroll
        for (int kt = 0; kt < 4; kt++)
            af[tt][4 + kt] = *(const short8*)&hbf[(size_t)mc * HID + kt * 32 + quad * 8];
    }

    floatx4 acc[2][8];
#pragma unroll
    for (int nt = 0; nt < 8; nt++) {
        floatx4 a0 = {0.f, 0.f, 0.f, 0.f}, a1 = {0.f, 0.f, 0.f, 0.f};
#pragma unroll
        for (int kt = 0; kt < 8; kt++) {
            short8 b = *(const short8*)&WT[(nt * 16 + ln15) * 256 + kt * 32 + quad * 8];
            a0 = __builtin_amdgcn_mfma_f32_16x16x32_bf16(af[0][kt], b, a0, 0, 0, 0);
            a1 = __builtin_amdgcn_mfma_f32_16x16x32_bf16(af[1][kt], b, a1, 0, 0, 0);
        }
        acc[0][nt] = a0; acc[1][nt] = a1;
    }

    float blv[8], gv[8], bv[8];
#pragma unroll
    for (int nt = 0; nt < 8; nt++) {
        int col = nt * 16 + ln15;
        blv[nt] = bl[col]; gv[nt] = g[col]; bv[nt] = bet[col];
    }

#pragma unroll
    for (int tt = 0; tt < 2; tt++) {
#pragma unroll
        for (int r = 0; r < 4; r++) {
            float s = 0.f;
#pragma unroll
            for (int nt = 0; nt < 8; nt++) s += acc[tt][nt][r] + blv[nt];
            s += __shfl_xor(s, 1); s += __shfl_xor(s, 2);
            s += __shfl_xor(s, 4); s += __shfl_xor(s, 8);
            float mu = s * (1.f / 128.f);
            float q = 0.f;
#pragma unroll
            for (int nt = 0; nt < 8; nt++) { float c = acc[tt][nt][r] + blv[nt] - mu; q += c * c; }
            q += __shfl_xor(q, 1); q += __shfl_xor(q, 2);
            q += __shfl_xor(q, 4); q += __shfl_xor(q, 8);
            float rstd = rsqrtf(q * (1.f / 128.f) + 1e-5f);
            int node = blkBase + tt * 64 + wave * 16 + quad * 4 + r;
            if (node < N) {
#pragma unroll
                for (int nt = 0; nt < 8; nt++) {
                    float y = fmaxf((acc[tt][nt][r] + blv[nt] - mu) * rstd * gv[nt] + bv[nt], 0.f);
                    hbf[(size_t)node * HID + nt * 16 + ln15] = f2bf16(y);
                }
            }
        }
    }
}

// ---------- SAGE final layer + P/Q epilogue: writes P (over hbf) and Q (over meanbf) ----------
__global__ __launch_bounds__(256) void sage_pq_mfma(
    unsigned short* __restrict__ hbf, unsigned short* __restrict__ mean_bf,
    const unsigned short* __restrict__ WT,
    const float* __restrict__ bl, const float* __restrict__ g,
    const float* __restrict__ bet, const unsigned short* __restrict__ W1T, int N) {
    __shared__ __align__(16) unsigned short sh[128 * SMS];   // 34816 B h-transpose
    const int t = threadIdx.x, wave = t >> 6, lane = t & 63;
    const int ln15 = lane & 15, quad = lane >> 4;
    const int blkBase = blockIdx.x * 128;

    short8 af[2][8];
#pragma unroll
    for (int tt = 0; tt < 2; tt++) {
        int m = blkBase + tt * 64 + wave * 16 + ln15;
        int mc = m < N ? m : N - 1;
#pragma unroll
        for (int kt = 0; kt < 4; kt++)
            af[tt][kt] = *(const short8*)&mean_bf[(size_t)mc * HID + kt * 32 + quad * 8];
#pragma unroll
        for (int kt = 0; kt < 4; kt++)
            af[tt][4 + kt] = *(const short8*)&hbf[(size_t)mc * HID + kt * 32 + quad * 8];
    }

    floatx4 acc[2][8];
#pragma unroll
    for (int nt = 0; nt < 8; nt++) {
        floatx4 a0 = {0.f, 0.f, 0.f, 0.f}, a1 = {0.f, 0.f, 0.f, 0.f};
#pragma unroll
        for (int kt = 0; kt < 8; kt++) {
            short8 b = *(const short8*)&WT[(nt * 16 + ln15) * 256 + kt * 32 + quad * 8];
            a0 = __builtin_amdgcn_mfma_f32_16x16x32_bf16(af[0][kt], b, a0, 0, 0, 0);
            a1 = __builtin_amdgcn_mfma_f32_16x16x32_bf16(af[1][kt], b, a1, 0, 0, 0);
        }
        acc[0][nt] = a0; acc[1][nt] = a1;
    }

    float blv[8], gv[8], bv[8];
#pragma unroll
    for (int nt = 0; nt < 8; nt++) {
        int col = nt * 16 + ln15;
        blv[nt] = bl[col]; gv[nt] = g[col]; bv[nt] = bet[col];
    }

#pragma unroll
    for (int tt = 0; tt < 2; tt++) {
#pragma unroll
        for (int r = 0; r < 4; r++) {
            float s = 0.f;
#pragma unroll
            for (int nt = 0; nt < 8; nt++) s += acc[tt][nt][r] + blv[nt];
            s += __shfl_xor(s, 1); s += __shfl_xor(s, 2);
            s += __shfl_xor(s, 4); s += __shfl_xor(s, 8);
            float mu = s * (1.f / 128.f);
            float q = 0.f;
#pragma unroll
            for (int nt = 0; nt < 8; nt++) { float c = acc[tt][nt][r] + blv[nt] - mu; q += c * c; }
            q += __shfl_xor(q, 1); q += __shfl_xor(q, 2);
            q += __shfl_xor(q, 4); q += __shfl_xor(q, 8);
            float rstd = rsqrtf(q * (1.f / 128.f) + 1e-5f);
            int row = tt * 64 + wave * 16 + quad * 4 + r;
#pragma unroll
            for (int nt = 0; nt < 8; nt++) {
                float y = fmaxf((acc[tt][nt][r] + blv[nt] - mu) * rstd * gv[nt] + bv[nt], 0.f);
                sh[row * SMS + nt * 16 + ln15] = f2bf16(y);
            }
        }
    }
    __syncthreads();   // block-wide: also orders af global reads before P/Q overwrite

    short8 hf[2][4];
#pragma unroll
    for (int tt = 0; tt < 2; tt++)
#pragma unroll
        for (int kt = 0; kt < 4; kt++)
            hf[tt][kt] = *(const short8*)&sh[(tt * 64 + wave * 16 + ln15) * SMS + kt * 32 + quad * 8];

#pragma unroll
    for (int nt = 0; nt < 8; nt++) {
#pragma unroll
        for (int sel = 0; sel < 2; sel++) {
            floatx4 a0 = {0.f, 0.f, 0.f, 0.f}, a1 = {0.f, 0.f, 0.f, 0.f};
#pragma unroll
            for (int kt = 0; kt < 4; kt++) {
                short8 b = *(const short8*)&W1T[(size_t)(nt * 16 + ln15) * K1 + sel * 128 + kt * 32 + quad * 8];
                a0 = __builtin_amdgcn_mfma_f32_16x16x32_bf16(hf[0][kt], b, a0, 0, 0, 0);
                a1 = __builtin_amdgcn_mfma_f32_16x16x32_bf16(hf[1][kt], b, a1, 0, 0, 0);
            }
            unsigned short* outp = sel ? mean_bf : hbf;
            floatx4 aa[2] = {a0, a1};
#pragma unroll
            for (int tt = 0; tt < 2; tt++) {
#pragma unroll
                for (int r = 0; r < 4; r++) {
                    int node = blkBase + tt * 64 + wave * 16 + quad * 4 + r;
                    if (node < N)
                        outp[(size_t)node * HID + nt * 16 + ln15] = f2bf16(aa[tt][r]);
                }
            }
        }
    }
}

// ---------- edge MLP v3: barrier-free, per-wave LDS slabs ----------
// wave w owns 16 edges (pos = blk*64 + w*16 + ln15); all LDS traffic wave-local.
__global__ __launch_bounds__(256) void edge_mlp_mfma(
    const unsigned short* __restrict__ Pbf, const unsigned short* __restrict__ Qbf,
    const int* __restrict__ csrS, const int* __restrict__ csrD, const int* __restrict__ csrE,
    const unsigned short* __restrict__ eattrP,
    const unsigned short* __restrict__ W1T, const float* __restrict__ b1,
    const unsigned short* __restrict__ W2T, const float* __restrict__ b2,
    const float* __restrict__ W3, const float* __restrict__ b3,
    float* __restrict__ out, int E)
{
    const int t = threadIdx.x;
    const int wave = t >> 6, lane = t & 63;
    const int ln15 = lane & 15, quad = lane >> 4;
    __shared__ __align__(16) char smem[4 * SLAB];    // 17920 B, one slab per wave
    char* slab = smem + wave * SLAB;
    unsigned short* sS = (unsigned short*)slab;      // [16][Z1S] bf16 (4352 B)
    float* sZ2 = (float*)slab;                       // [16][Z2S] fp32 (4416 B), overlays sS

    const int eBase = blockIdx.x * ET;
    const int pos = eBase + wave * 16 + ln15;
    const int pc = pos < E ? pos : E - 1;
    const int rs = csrS[pc], rd = csrD[pc];

    short8 pf[4], qf[4];
#pragma unroll
    for (int kt = 0; kt < 4; kt++)
        pf[kt] = *(const short8*)&Pbf[(size_t)rs * HID + kt * 32 + quad * 8];
#pragma unroll
    for (int kt = 0; kt < 4; kt++)
        qf[kt] = *(const short8*)&Qbf[(size_t)rd * HID + kt * 32 + quad * 8];

    // eattr in CSR order, bf16, contiguous: 24 B/edge
    short8 ef = {0, 0, 0, 0, 0, 0, 0, 0};
    {
        const unsigned* ep = (const unsigned*)(eattrP + (size_t)pc * 12);
        unsigned* eu = (unsigned*)&ef;
        if (quad == 0) {
            eu[0] = ep[0]; eu[1] = ep[1]; eu[2] = ep[2]; eu[3] = ep[3];
        } else if (quad == 1) {
            eu[0] = ep[4]; eu[1] = ep[5];
        }
    }

    // S = eattr @ W1c + b1 -> wave-local LDS (C-layout rows quad*4+r, local 0..15)
#pragma unroll
    for (int nt = 0; nt < 8; nt++) {
        floatx4 sa = {0.f, 0.f, 0.f, 0.f};
        short8 b = *(const short8*)&W1T[(size_t)(nt * 16 + ln15) * K1 + 256 + quad * 8];
        sa = __builtin_amdgcn_mfma_f32_16x16x32_bf16(ef, b, sa, 0, 0, 0);
        float bias = b1[nt * 16 + ln15];
#pragma unroll
        for (int r = 0; r < 4; r++)
            sS[(quad * 4 + r) * Z1S + nt * 16 + ln15] = f2bf16(sa[r] + bias);
    }
    // wave-local LDS RAW: compiler orders via lgkmcnt (no barrier needed)

    // z1 = relu(P + Q + S), A-layout read: local row ln15
    short8 zf[4];
#pragma unroll
    for (int kt = 0; kt < 4; kt++) {
        short8 s8 = *(const short8*)&sS[ln15 * Z1S + kt * 32 + quad * 8];
#pragma unroll
        for (int w = 0; w < 4; w++) {
            unsigned up = ((unsigned*)&pf[kt])[w];
            unsigned uq = ((unsigned*)&qf[kt])[w];
            unsigned us = ((unsigned*)&s8)[w];
            float lo = bf2f_lo(up) + bf2f_lo(uq) + bf2f_lo(us);
            float hi = bf2f_hi(up) + bf2f_hi(uq) + bf2f_hi(us);
            ((unsigned*)&zf[kt])[w] = pack2bf(fmaxf(lo, 0.f), fmaxf(hi, 0.f));
        }
    }

    // layer 2: [16 x 128] -> [16 x 64], z2 into wave-local slab (overlays sS; in-wave order ok)
#pragma unroll
    for (int nt = 0; nt < 4; nt++) {
        floatx4 a = {0.f, 0.f, 0.f, 0.f};
#pragma unroll
        for (int kt = 0; kt < 4; kt++) {
            short8 b = *(const short8*)&W2T[(nt * 16 + ln15) * HID + kt * 32 + quad * 8];
            a = __builtin_amdgcn_mfma_f32_16x16x32_bf16(zf[kt], b, a, 0, 0, 0);
        }
        float bias = b2[nt * 16 + ln15];
#pragma unroll
        for (int r = 0; r < 4; r++)
            sZ2[(quad * 4 + r) * Z2S + nt * 16 + ln15] = fmaxf(a[r] + bias, 0.f);
    }

    // layer 3 + softplus: 4 lanes per edge, wave-local (16 FMAs + 2 shuffles)
    {
        int eo = lane >> 2, q = lane & 3;        // eo 0..15 within wave
        int p = eBase + wave * 16 + eo;
        float a3 = 0.f;
        const float* z2 = sZ2 + eo * Z2S + q * 16;
#pragma unroll
        for (int k = 0; k < 16; k++) a3 = fmaf(z2[k], W3[q * 16 + k], a3);
        a3 += __shfl_xor(a3, 1);
        a3 += __shfl_xor(a3, 2);
        if (q == 0 && p < E) {
            a3 += b3[0];
            out[csrE[p]] = fmaxf(a3, 0.f) + log1pf(expf(-fabsf(a3)));
        }
    }
}

extern "C" void kernel_launch(void* const* d_in, const int* in_sizes, int n_in,
                              void* d_out, int out_size, void* d_ws, size_t ws_size,
                              hipStream_t stream) {
    const float* x       = (const float*)d_in[0];
    const int*   ei      = (const int*)d_in[1];
    const float* eattr   = (const float*)d_in[2];
    const float* node_W  = (const float*)d_in[3];
    const float* node_b  = (const float*)d_in[4];
    const float* sage_Wl = (const float*)d_in[5];
    const float* sage_bl = (const float*)d_in[6];
    const float* sage_Wr = (const float*)d_in[7];
    const float* ln_g    = (const float*)d_in[8];
    const float* ln_b    = (const float*)d_in[9];
    const float* W1 = (const float*)d_in[10];
    const float* b1 = (const float*)d_in[11];
    const float* W2 = (const float*)d_in[12];
    const float* b2 = (const float*)d_in[13];
    const float* W3 = (const float*)d_in[14];
    const float* b3 = (const float*)d_in[15];
    float* out = (float*)d_out;

    const int N = in_sizes[0] / 5;
    const int E = in_sizes[1] / 2;
    const int* src  = ei;
    const int* dstp = ei + E;

    char* ws = (char*)d_ws;
    size_t cur_off = 0;
    auto alloc = [&](size_t bytes) { size_t p = cur_off; cur_off = (cur_off + bytes + 255) & ~(size_t)255; return p; };
    unsigned short* hbf    = (unsigned short*)(ws + alloc((size_t)N * HID * 2));  // h, later P
    unsigned short* meanbf = (unsigned short*)(ws + alloc((size_t)N * HID * 2));  // mean, later Q
    int*            csrS   = (int*)(ws + alloc((size_t)E * 4));
    int*            csrD   = (int*)(ws + alloc((size_t)E * 4));
    int*            csrE   = (int*)(ws + alloc((size_t)E * 4));
    unsigned short* eattrP = (unsigned short*)(ws + alloc((size_t)E * 12 * 2));
    unsigned*       degu   = (unsigned*)(ws + alloc((size_t)N * 4));
    unsigned*       curp   = (unsigned*)(ws + alloc((size_t)N * 4));
    unsigned*       offs   = (unsigned*)(ws + alloc((size_t)N * 4));
    unsigned*       bsum   = (unsigned*)(ws + alloc(64 * 4));
    unsigned short* W1T    = (unsigned short*)(ws + alloc(128 * K1 * 2));
    unsigned short* W2T    = (unsigned short*)(ws + alloc(64 * HID * 2));
    unsigned short* WST    = (unsigned short*)(ws + alloc(3 * 128 * 256 * 2));

    hipMemsetAsync(degu, 0, (size_t)N * sizeof(unsigned), stream);
    hist_kernel<<<(E + 255) / 256, 256, 0, stream>>>(dstp, degu, E);
    int NB = (N + 2047) / 2048;
    scan_partial<<<NB, 256, 0, stream>>>(degu, offs, bsum, N);
    scan_bsum<<<1, 64, 0, stream>>>(bsum, NB);
    scan_add<<<(N + 255) / 256, 256, 0, stream>>>(offs, bsum, curp, N);
    csr_fill<<<(E + 255) / 256, 256, 0, stream>>>(src, dstp, eattr, offs, curp,
                                                  csrS, csrD, csrE, eattrP, E);

    int prepTotal = 128 * K1 + 64 * HID + 3 * 128 * 256;
    prep_weights<<<(prepTotal + 255) / 256, 256, 0, stream>>>(W1, W2, sage_Wl, sage_Wr, W1T, W2T, WST);

    node_proj_kernel<<<(N * 64 + 255) / 256, 256, 0, stream>>>(x, node_W, node_b, hbf, N);

    int nblk = (N + 127) / 128;
    for (int l = 0; l < 2; l++) {
        agg_csr<<<(N + 15) / 16, 256, 0, stream>>>(hbf, csrS, offs, degu, meanbf, N);
        sage_mfma<<<nblk, 256, 0, stream>>>(
            hbf, meanbf, WST + (size_t)l * 128 * 256,
            sage_bl + (size_t)l * HID, ln_g + (size_t)l * HID, ln_b + (size_t)l * HID, N);
    }
    agg_csr<<<(N + 15) / 16, 256, 0, stream>>>(hbf, csrS, offs, degu, meanbf, N);
    sage_pq_mfma<<<nblk, 256, 0, stream>>>(
        hbf, meanbf, WST + (size_t)2 * 128 * 256,
        sage_bl + (size_t)2 * HID, ln_g + (size_t)2 * HID, ln_b + (size_t)2 * HID, W1T, N);

    edge_mlp_mfma<<<(E + ET - 1) / ET, 256, 0, stream>>>(
        hbf, meanbf, csrS, csrD, csrE, eattrP, W1T, b1, W2T, b2, W3, b3, out, E);
}

// Round 12
// 672.781 us; speedup vs baseline: 1.0043x; 1.0043x over previous
//
#include <hip/hip_runtime.h>
#include <hip/hip_bf16.h>
#include <math.h>

#define HID 128
#define ET  64          // edges per block (edge MLP), 1 M-tile per wave
#define K1  288         // padded K for layer 1 (268 -> 9*32)
#define Z1S 136         // S LDS stride in bf16
#define Z2S 69          // z2 LDS stride in fp32
#define SMS 136         // sage_pq h-transpose LDS stride in bf16

typedef __attribute__((ext_vector_type(8))) short short8;   // 8 bf16 = 4 VGPRs
typedef __attribute__((ext_vector_type(4))) float floatx4;  // MFMA accumulator

// HW packed convert: v_cvt_pk_bf16_f32 (RNE), lo -> low 16 bits
static __device__ __forceinline__ unsigned pack2bf(float lo, float hi) {
    __hip_bfloat162 v = __float22bfloat162_rn(float2{lo, hi});
    union { __hip_bfloat162 b; unsigned u; } cv; cv.b = v; return cv.u;
}
static __device__ __forceinline__ unsigned short f2bf16(float v) {
    return (unsigned short)pack2bf(v, v);
}
static __device__ __forceinline__ float bf2f_lo(unsigned u) { return __uint_as_float(u << 16); }
static __device__ __forceinline__ float bf2f_hi(unsigned u) { return __uint_as_float(u & 0xffff0000u); }

// ---------- CSR build ----------
__global__ void hist_kernel(const int* __restrict__ dst, unsigned* __restrict__ deg, int E) {
    int e = blockIdx.x * 256 + threadIdx.x;
    if (e < E) atomicAdd(&deg[dst[e]], 1u);
}

__global__ __launch_bounds__(256) void scan_partial(const unsigned* __restrict__ deg,
        unsigned* __restrict__ off, unsigned* __restrict__ bsum, int N) {
    int t = threadIdx.x;
    int base = blockIdx.x * 2048 + t * 8;
    unsigned v[8]; unsigned run = 0;
#pragma unroll
    for (int i = 0; i < 8; i++) {
        int g = base + i;
        unsigned d = (g < N) ? deg[g] : 0u;
        v[i] = run; run += d;
    }
    __shared__ unsigned s[256];
    s[t] = run; __syncthreads();
    for (int o2 = 1; o2 < 256; o2 <<= 1) {
        unsigned x = (t >= o2) ? s[t - o2] : 0u;
        __syncthreads();
        s[t] += x;
        __syncthreads();
    }
    unsigned texcl = (t > 0) ? s[t - 1] : 0u;
    if (t == 255) bsum[blockIdx.x] = s[255];
#pragma unroll
    for (int i = 0; i < 8; i++) {
        int g = base + i;
        if (g < N) off[g] = texcl + v[i];
    }
}

__global__ void scan_bsum(unsigned* bsum, int B) {   // B <= 64, single wave inclusive
    int t = threadIdx.x;
    unsigned v = (t < B) ? bsum[t] : 0u;
    for (int o = 1; o < 64; o <<= 1) {
        unsigned x = __shfl_up(v, o);
        if (t >= o) v += x;
    }
    if (t < B) bsum[t] = v;
}

__global__ void scan_add(unsigned* __restrict__ off, const unsigned* __restrict__ bsum,
                         unsigned* __restrict__ cur, int N) {
    int g = blockIdx.x * 256 + threadIdx.x;
    if (g >= N) return;
    cur[g] = 0u;
    int blk = g >> 11;
    if (blk > 0) off[g] += bsum[blk - 1];
}

// fills: csrS/csrD/csrE + eattr copied into CSR order as bf16 (24 B/edge)
__global__ void csr_fill(const int* __restrict__ src, const int* __restrict__ dst,
                         const float* __restrict__ eattr,
                         const unsigned* __restrict__ off, unsigned* __restrict__ cur,
                         int* __restrict__ csrS, int* __restrict__ csrD,
                         int* __restrict__ csrE, unsigned short* __restrict__ eattrP, int E) {
    int e = blockIdx.x * 256 + threadIdx.x;
    if (e >= E) return;
    int d = dst[e];
    unsigned p = off[d] + atomicAdd(&cur[d], 1u);
    csrS[p] = src[e];
    csrD[p] = d;
    csrE[p] = e;
    const float* ep = eattr + (size_t)e * 12;
    float4 v0 = *(const float4*)ep;
    float4 v1 = *(const float4*)(ep + 4);
    float4 v2 = *(const float4*)(ep + 8);
    unsigned* op = (unsigned*)(eattrP + (size_t)p * 12);
    op[0] = pack2bf(v0.x, v0.y); op[1] = pack2bf(v0.z, v0.w);
    op[2] = pack2bf(v1.x, v1.y); op[3] = pack2bf(v1.z, v1.w);
    op[4] = pack2bf(v2.x, v2.y); op[5] = pack2bf(v2.z, v2.w);
}

// ---------- node projection + weight prep (merged, one dispatch) ----------
#define PREP_TOTAL (128 * K1 + 64 * HID + 3 * 128 * 256)
__global__ void prep_all(const float* __restrict__ x, const float* __restrict__ nW,
                         const float* __restrict__ nb, unsigned short* __restrict__ hbf, int N,
                         const float* __restrict__ W1, const float* __restrict__ W2,
                         const float* __restrict__ Wl, const float* __restrict__ Wr,
                         unsigned short* __restrict__ W1T, unsigned short* __restrict__ W2T,
                         unsigned short* __restrict__ WST) {
    int i = blockIdx.x * 256 + threadIdx.x;
    if (i < N * 64) {
        int n = i >> 6, f2 = (i & 63) * 2;
        float a0 = nb[f2], a1 = nb[f2 + 1];
#pragma unroll
        for (int k = 0; k < 5; k++) {
            float xv = x[n * 5 + k];
            a0 = fmaf(xv, nW[k * HID + f2], a0);
            a1 = fmaf(xv, nW[k * HID + f2 + 1], a1);
        }
        *(unsigned*)&hbf[(size_t)n * HID + f2] = pack2bf(a0, a1);
        return;
    }
    i -= N * 64;
    if (i < 128 * K1) {
        int n = i / K1, k = i - n * K1;
        W1T[i] = (k < 268) ? f2bf16(W1[k * HID + n]) : (unsigned short)0;
        return;
    }
    int j = i - 128 * K1;
    if (j < 64 * HID) {
        int n = j >> 7, k = j & 127;
        W2T[j] = f2bf16(W2[k * 64 + n]);
        return;
    }
    int m = j - 64 * HID;
    if (m < 3 * 128 * 256) {
        int l = m >> 15, rem = m & 32767, n = rem >> 8, k = rem & 255;
        float v = (k < 128) ? Wl[l * 16384 + k * 128 + n] : Wr[l * 16384 + (k - 128) * 128 + n];
        WST[m] = f2bf16(v);
    }
}

// ---------- mean aggregation: 4 nodes per wave, 8 rows in flight per group ----------
__global__ __launch_bounds__(256) void agg_csr(const unsigned short* __restrict__ hbf,
        const int* __restrict__ csr, const unsigned* __restrict__ off,
        const unsigned* __restrict__ degu, unsigned short* __restrict__ mean_bf, int N) {
    const int wv = threadIdx.x >> 6, lane = threadIdx.x & 63;
    const int g = lane >> 4, c = lane & 15;
    const int n = (blockIdx.x * 4 + wv) * 4 + g;
    const int nc = n < N ? n : N - 1;
    const unsigned o = off[nc];
    const unsigned d = (n < N) ? degu[nc] : 0u;
    unsigned dmax = d;
    dmax = max(dmax, (unsigned)__shfl_xor((int)dmax, 16));
    dmax = max(dmax, (unsigned)__shfl_xor((int)dmax, 32));

    float acc[8] = {0.f, 0.f, 0.f, 0.f, 0.f, 0.f, 0.f, 0.f};
    for (unsigned i = 0; i < dmax; i += 8) {
        uint4 v[8];
#pragma unroll
        for (int j = 0; j < 8; j++) {
            unsigned p = (i + j < d) ? o + i + j : 0u;
            int s = csr[p];
            v[j] = *(const uint4*)&hbf[(size_t)s * HID + c * 8];
        }
#pragma unroll
        for (int j = 0; j < 8; j++) {
            if (i + j < d) {
                acc[0] += bf2f_lo(v[j].x); acc[1] += bf2f_hi(v[j].x);
                acc[2] += bf2f_lo(v[j].y); acc[3] += bf2f_hi(v[j].y);
                acc[4] += bf2f_lo(v[j].z); acc[5] += bf2f_hi(v[j].z);
                acc[6] += bf2f_lo(v[j].w); acc[7] += bf2f_hi(v[j].w);
            }
        }
    }
    if (n < N) {
        float inv = d ? 1.f / (float)d : 0.f;
        uint4 p;
        p.x = pack2bf(acc[0] * inv, acc[1] * inv);
        p.y = pack2bf(acc[2] * inv, acc[3] * inv);
        p.z = pack2bf(acc[4] * inv, acc[5] * inv);
        p.w = pack2bf(acc[6] * inv, acc[7] * inv);
        *(uint4*)&mean_bf[(size_t)n * HID + c * 8] = p;
    }
}

// ---------- SAGE layer (layers 0,1): h in-place, no LDS ----------
__global__ __launch_bounds__(256) void sage_mfma(
    unsigned short* __restrict__ hbf, const unsigned short* __restrict__ mean_bf,
    const unsigned short* __restrict__ WT,
    const float* __restrict__ bl, const float* __restrict__ g,
    const float* __restrict__ bet, int N) {
    const int t = threadIdx.x, wave = t >> 6, lane = t & 63;
    const int ln15 = lane & 15, quad = lane >> 4;
    const int blkBase = blockIdx.x * 128;

    short8 af[2][8];
#pragma unroll
    for (int tt = 0; tt < 2; tt++) {
        int m = blkBase + tt * 64 + wave * 16 + ln15;
        int mc = m < N ? m : N - 1;
#pragma unroll
        for (int kt = 0; kt < 4; kt++)
            af[tt][kt] = *(const short8*)&mean_bf[(size_t)mc * HID + kt * 32 + quad * 8];
#pragma unroll
        for (int kt = 0; kt < 4; kt++)
            af[tt][4 + kt] = *(const short8*)&hbf[(size_t)mc * HID + kt * 32 + quad * 8];
    }

    floatx4 acc[2][8];
#pragma unroll
    for (int nt = 0; nt < 8; nt++) {
        floatx4 a0 = {0.f, 0.f, 0.f, 0.f}, a1 = {0.f, 0.f, 0.f, 0.f};
#pragma unroll
        for (int kt = 0; kt < 8; kt++) {
            short8 b = *(const short8*)&WT[(nt * 16 + ln15) * 256 + kt * 32 + quad * 8];
            a0 = __builtin_amdgcn_mfma_f32_16x16x32_bf16(af[0][kt], b, a0, 0, 0, 0);
            a1 = __builtin_amdgcn_mfma_f32_16x16x32_bf16(af[1][kt], b, a1, 0, 0, 0);
        }
        acc[0][nt] = a0; acc[1][nt] = a1;
    }

    float blv[8], gv[8], bv[8];
#pragma unroll
    for (int nt = 0; nt < 8; nt++) {
        int col = nt * 16 + ln15;
        blv[nt] = bl[col]; gv[nt] = g[col]; bv[nt] = bet[col];
    }

#pragma unroll
    for (int tt = 0; tt < 2; tt++) {
#pragma unroll
        for (int r = 0; r < 4; r++) {
            float s = 0.f;
#pragma unroll
            for (int nt = 0; nt < 8; nt++) s += acc[tt][nt][r] + blv[nt];
            s += __shfl_xor(s, 1); s += __shfl_xor(s, 2);
            s += __shfl_xor(s, 4); s += __shfl_xor(s, 8);
            float mu = s * (1.f / 128.f);
            float q = 0.f;
#pragma unroll
            for (int nt = 0; nt < 8; nt++) { float c = acc[tt][nt][r] + blv[nt] - mu; q += c * c; }
            q += __shfl_xor(q, 1); q += __shfl_xor(q, 2);
            q += __shfl_xor(q, 4); q += __shfl_xor(q, 8);
            float rstd = rsqrtf(q * (1.f / 128.f) + 1e-5f);
            int node = blkBase + tt * 64 + wave * 16 + quad * 4 + r;
            if (node < N) {
#pragma unroll
                for (int nt = 0; nt < 8; nt++) {
                    float y = fmaxf((acc[tt][nt][r] + blv[nt] - mu) * rstd * gv[nt] + bv[nt], 0.f);
                    hbf[(size_t)node * HID + nt * 16 + ln15] = f2bf16(y);
                }
            }
        }
    }
}

// ---------- SAGE final layer + P/Q epilogue: writes P (over hbf) and Q (over meanbf) ----------
__global__ __launch_bounds__(256) void sage_pq_mfma(
    unsigned short* __restrict__ hbf, unsigned short* __restrict__ mean_bf,
    const unsigned short* __restrict__ WT,
    const float* __restrict__ bl, const float* __restrict__ g,
    const float* __restrict__ bet, const unsigned short* __restrict__ W1T, int N) {
    __shared__ __align__(16) unsigned short sh[128 * SMS];   // 34816 B h-transpose
    const int t = threadIdx.x, wave = t >> 6, lane = t & 63;
    const int ln15 = lane & 15, quad = lane >> 4;
    const int blkBase = blockIdx.x * 128;

    short8 af[2][8];
#pragma unroll
    for (int tt = 0; tt < 2; tt++) {
        int m = blkBase + tt * 64 + wave * 16 + ln15;
        int mc = m < N ? m : N - 1;
#pragma unroll
        for (int kt = 0; kt < 4; kt++)
            af[tt][kt] = *(const short8*)&mean_bf[(size_t)mc * HID + kt * 32 + quad * 8];
#pragma unroll
        for (int kt = 0; kt < 4; kt++)
            af[tt][4 + kt] = *(const short8*)&hbf[(size_t)mc * HID + kt * 32 + quad * 8];
    }

    floatx4 acc[2][8];
#pragma unroll
    for (int nt = 0; nt < 8; nt++) {
        floatx4 a0 = {0.f, 0.f, 0.f, 0.f}, a1 = {0.f, 0.f, 0.f, 0.f};
#pragma unroll
        for (int kt = 0; kt < 8; kt++) {
            short8 b = *(const short8*)&WT[(nt * 16 + ln15) * 256 + kt * 32 + quad * 8];
            a0 = __builtin_amdgcn_mfma_f32_16x16x32_bf16(af[0][kt], b, a0, 0, 0, 0);
            a1 = __builtin_amdgcn_mfma_f32_16x16x32_bf16(af[1][kt], b, a1, 0, 0, 0);
        }
        acc[0][nt] = a0; acc[1][nt] = a1;
    }

    float blv[8], gv[8], bv[8];
#pragma unroll
    for (int nt = 0; nt < 8; nt++) {
        int col = nt * 16 + ln15;
        blv[nt] = bl[col]; gv[nt] = g[col]; bv[nt] = bet[col];
    }

#pragma unroll
    for (int tt = 0; tt < 2; tt++) {
#pragma unroll
        for (int r = 0; r < 4; r++) {
            float s = 0.f;
#pragma unroll
            for (int nt = 0; nt < 8; nt++) s += acc[tt][nt][r] + blv[nt];
            s += __shfl_xor(s, 1); s += __shfl_xor(s, 2);
            s += __shfl_xor(s, 4); s += __shfl_xor(s, 8);
            float mu = s * (1.f / 128.f);
            float q = 0.f;
#pragma unroll
            for (int nt = 0; nt < 8; nt++) { float c = acc[tt][nt][r] + blv[nt] - mu; q += c * c; }
            q += __shfl_xor(q, 1); q += __shfl_xor(q, 2);
            q += __shfl_xor(q, 4); q += __shfl_xor(q, 8);
            float rstd = rsqrtf(q * (1.f / 128.f) + 1e-5f);
            int row = tt * 64 + wave * 16 + quad * 4 + r;
#pragma unroll
            for (int nt = 0; nt < 8; nt++) {
                float y = fmaxf((acc[tt][nt][r] + blv[nt] - mu) * rstd * gv[nt] + bv[nt], 0.f);
                sh[row * SMS + nt * 16 + ln15] = f2bf16(y);
            }
        }
    }
    __syncthreads();   // block-wide: also orders af global reads before P/Q overwrite

    short8 hf[2][4];
#pragma unroll
    for (int tt = 0; tt < 2; tt++)
#pragma unroll
        for (int kt = 0; kt < 4; kt++)
            hf[tt][kt] = *(const short8*)&sh[(tt * 64 + wave * 16 + ln15) * SMS + kt * 32 + quad * 8];

#pragma unroll
    for (int nt = 0; nt < 8; nt++) {
#pragma unroll
        for (int sel = 0; sel < 2; sel++) {
            floatx4 a0 = {0.f, 0.f, 0.f, 0.f}, a1 = {0.f, 0.f, 0.f, 0.f};
#pragma unroll
            for (int kt = 0; kt < 4; kt++) {
                short8 b = *(const short8*)&W1T[(size_t)(nt * 16 + ln15) * K1 + sel * 128 + kt * 32 + quad * 8];
                a0 = __builtin_amdgcn_mfma_f32_16x16x32_bf16(hf[0][kt], b, a0, 0, 0, 0);
                a1 = __builtin_amdgcn_mfma_f32_16x16x32_bf16(hf[1][kt], b, a1, 0, 0, 0);
            }
            unsigned short* outp = sel ? mean_bf : hbf;
            floatx4 aa[2] = {a0, a1};
#pragma unroll
            for (int tt = 0; tt < 2; tt++) {
#pragma unroll
                for (int r = 0; r < 4; r++) {
                    int node = blkBase + tt * 64 + wave * 16 + quad * 4 + r;
                    if (node < N)
                        outp[(size_t)node * HID + nt * 16 + ln15] = f2bf16(aa[tt][r]);
                }
            }
        }
    }
}

// ---------- edge MLP (R10 structure) + occupancy hint ----------
__global__ __launch_bounds__(256, 8) void edge_mlp_mfma(
    const unsigned short* __restrict__ Pbf, const unsigned short* __restrict__ Qbf,
    const int* __restrict__ csrS, const int* __restrict__ csrD, const int* __restrict__ csrE,
    const unsigned short* __restrict__ eattrP,
    const unsigned short* __restrict__ W1T, const float* __restrict__ b1,
    const unsigned short* __restrict__ W2T, const float* __restrict__ b2,
    const float* __restrict__ W3, const float* __restrict__ b3,
    float* __restrict__ out, int E)
{
    const int t = threadIdx.x;
    const int eBase = blockIdx.x * ET;
    __shared__ __align__(16) char smem[ET * Z2S * 4];   // 17664 B: S bf16 [64][136] / z2 fp32 [64][69]
    unsigned short* sS = (unsigned short*)smem;
    float* sZ2 = (float*)smem;

    const int wave = t >> 6, lane = t & 63;
    const int ln15 = lane & 15, quad = lane >> 4;
    const int rowb = wave * 16 + ln15;
    const int pos = eBase + rowb;
    const int pc = pos < E ? pos : E - 1;
    const int rs = csrS[pc], rd = csrD[pc];

    short8 pf[4], qf[4];
#pragma unroll
    for (int kt = 0; kt < 4; kt++)
        pf[kt] = *(const short8*)&Pbf[(size_t)rs * HID + kt * 32 + quad * 8];
#pragma unroll
    for (int kt = 0; kt < 4; kt++)
        qf[kt] = *(const short8*)&Qbf[(size_t)rd * HID + kt * 32 + quad * 8];

    // eattr in CSR order, bf16, contiguous: 24 B/edge
    short8 ef = {0, 0, 0, 0, 0, 0, 0, 0};
    {
        const unsigned* ep = (const unsigned*)(eattrP + (size_t)pc * 12);
        unsigned* eu = (unsigned*)&ef;
        if (quad == 0) {
            eu[0] = ep[0]; eu[1] = ep[1]; eu[2] = ep[2]; eu[3] = ep[3];
        } else if (quad == 1) {
            eu[0] = ep[4]; eu[1] = ep[5];
        }
    }

    // S = eattr @ W1c + b1 (K=[256,288) slice of W1T) -> LDS C-layout, 2B stores
#pragma unroll
    for (int nt = 0; nt < 8; nt++) {
        floatx4 sa = {0.f, 0.f, 0.f, 0.f};
        short8 b = *(const short8*)&W1T[(size_t)(nt * 16 + ln15) * K1 + 256 + quad * 8];
        sa = __builtin_amdgcn_mfma_f32_16x16x32_bf16(ef, b, sa, 0, 0, 0);
        float bias = b1[nt * 16 + ln15];
#pragma unroll
        for (int r = 0; r < 4; r++) {
            int row = wave * 16 + quad * 4 + r;
            sS[row * Z1S + nt * 16 + ln15] = f2bf16(sa[r] + bias);
        }
    }
    __syncthreads();

    // z1 = relu(P + Q + S), pairwise with HW packed cvt
    short8 zf[4];
#pragma unroll
    for (int kt = 0; kt < 4; kt++) {
        short8 s8 = *(const short8*)&sS[rowb * Z1S + kt * 32 + quad * 8];
#pragma unroll
        for (int w = 0; w < 4; w++) {
            unsigned up = ((unsigned*)&pf[kt])[w];
            unsigned uq = ((unsigned*)&qf[kt])[w];
            unsigned us = ((unsigned*)&s8)[w];
            float lo = bf2f_lo(up) + bf2f_lo(uq) + bf2f_lo(us);
            float hi = bf2f_hi(up) + bf2f_hi(uq) + bf2f_hi(us);
            ((unsigned*)&zf[kt])[w] = pack2bf(fmaxf(lo, 0.f), fmaxf(hi, 0.f));
        }
    }
    __syncthreads();    // all S reads done before z2 overlays

    // layer 2: [64 x 128] -> [64 x 64]
#pragma unroll
    for (int nt = 0; nt < 4; nt++) {
        floatx4 a = {0.f, 0.f, 0.f, 0.f};
#pragma unroll
        for (int kt = 0; kt < 4; kt++) {
            short8 b = *(const short8*)&W2T[(nt * 16 + ln15) * HID + kt * 32 + quad * 8];
            a = __builtin_amdgcn_mfma_f32_16x16x32_bf16(zf[kt], b, a, 0, 0, 0);
        }
        float bias = b2[nt * 16 + ln15];
#pragma unroll
        for (int r = 0; r < 4; r++) {
            int row = wave * 16 + quad * 4 + r;
            sZ2[row * Z2S + nt * 16 + ln15] = fmaxf(a[r] + bias, 0.f);
        }
    }
    __syncthreads();

    // layer 3 + softplus (fp32), one thread per position; scattered write to out[edge]
    if (t < ET) {
        int p = eBase + t;
        if (p < E) {
            float a3 = b3[0];
            const float* z2 = sZ2 + t * Z2S;
#pragma unroll
            for (int k = 0; k < 64; k++) a3 = fmaf(z2[k], W3[k], a3);
            out[csrE[p]] = fmaxf(a3, 0.f) + log1pf(expf(-fabsf(a3)));
        }
    }
}

extern "C" void kernel_launch(void* const* d_in, const int* in_sizes, int n_in,
                              void* d_out, int out_size, void* d_ws, size_t ws_size,
                              hipStream_t stream) {
    const float* x       = (const float*)d_in[0];
    const int*   ei      = (const int*)d_in[1];
    const float* eattr   = (const float*)d_in[2];
    const float* node_W  = (const float*)d_in[3];
    const float* node_b  = (const float*)d_in[4];
    const float* sage_Wl = (const float*)d_in[5];
    const float* sage_bl = (const float*)d_in[6];
    const float* sage_Wr = (const float*)d_in[7];
    const float* ln_g    = (const float*)d_in[8];
    const float* ln_b    = (const float*)d_in[9];
    const float* W1 = (const float*)d_in[10];
    const float* b1 = (const float*)d_in[11];
    const float* W2 = (const float*)d_in[12];
    const float* b2 = (const float*)d_in[13];
    const float* W3 = (const float*)d_in[14];
    const float* b3 = (const float*)d_in[15];
    float* out = (float*)d_out;

    const int N = in_sizes[0] / 5;
    const int E = in_sizes[1] / 2;
    const int* src  = ei;
    const int* dstp = ei + E;

    char* ws = (char*)d_ws;
    size_t cur_off = 0;
    auto alloc = [&](size_t bytes) { size_t p = cur_off; cur_off = (cur_off + bytes + 255) & ~(size_t)255; return p; };
    unsigned short* hbf    = (unsigned short*)(ws + alloc((size_t)N * HID * 2));  // h, later P
    unsigned short* meanbf = (unsigned short*)(ws + alloc((size_t)N * HID * 2));  // mean, later Q
    int*            csrS   = (int*)(ws + alloc((size_t)E * 4));
    int*            csrD   = (int*)(ws + alloc((size_t)E * 4));
    int*            csrE   = (int*)(ws + alloc((size_t)E * 4));
    unsigned short* eattrP = (unsigned short*)(ws + alloc((size_t)E * 12 * 2));
    unsigned*       degu   = (unsigned*)(ws + alloc((size_t)N * 4));
    unsigned*       curp   = (unsigned*)(ws + alloc((size_t)N * 4));
    unsigned*       offs   = (unsigned*)(ws + alloc((size_t)N * 4));
    unsigned*       bsum   = (unsigned*)(ws + alloc(64 * 4));
    unsigned short* W1T    = (unsigned short*)(ws + alloc(128 * K1 * 2));
    unsigned short* W2T    = (unsigned short*)(ws + alloc(64 * HID * 2));
    unsigned short* WST    = (unsigned short*)(ws + alloc(3 * 128 * 256 * 2));

    hipMemsetAsync(degu, 0, (size_t)N * sizeof(unsigned), stream);
    hist_kernel<<<(E + 255) / 256, 256, 0, stream>>>(dstp, degu, E);
    int NB = (N + 2047) / 2048;
    scan_partial<<<NB, 256, 0, stream>>>(degu, offs, bsum, N);
    scan_bsum<<<1, 64, 0, stream>>>(bsum, NB);
    scan_add<<<(N + 255) / 256, 256, 0, stream>>>(offs, bsum, curp, N);
    csr_fill<<<(E + 255) / 256, 256, 0, stream>>>(src, dstp, eattr, offs, curp,
                                                  csrS, csrD, csrE, eattrP, E);

    int prepGrid = (N * 64 + PREP_TOTAL + 255) / 256;
    prep_all<<<prepGrid, 256, 0, stream>>>(x, node_W, node_b, hbf, N,
                                           W1, W2, sage_Wl, sage_Wr, W1T, W2T, WST);

    int nblk = (N + 127) / 128;
    for (int l = 0; l < 2; l++) {
        agg_csr<<<(N + 15) / 16, 256, 0, stream>>>(hbf, csrS, offs, degu, meanbf, N);
        sage_mfma<<<nblk, 256, 0, stream>>>(
            hbf, meanbf, WST + (size_t)l * 128 * 256,
            sage_bl + (size_t)l * HID, ln_g + (size_t)l * HID, ln_b + (size_t)l * HID, N);
    }
    agg_csr<<<(N + 15) / 16, 256, 0, stream>>>(hbf, csrS, offs, degu, meanbf, N);
    sage_pq_mfma<<<nblk, 256, 0, stream>>>(
        hbf, meanbf, WST + (size_t)2 * 128 * 256,
        sage_bl + (size_t)2 * HID, ln_g + (size_t)2 * HID, ln_b + (size_t)2 * HID, W1T, N);

    edge_mlp_mfma<<<(E + ET - 1) / ET, 256, 0, stream>>>(
        hbf, meanbf, csrS, csrD, csrE, eattrP, W1T, b1, W2T, b2, W3, b3, out, E);
}